// Round 9
// baseline (450.103 us; speedup 1.0000x reference)
//
#include <hip/hip_runtime.h>

// CircuitModel: sequential Oja/Hebbian plasticity scan.
//   y_t = sigmoid(w_t.x_t); w_{t+1} = b_t*w_t + a_t*x_t,
//   a_t = lr*th0*y_t, b_t = 1 + lr*th1*y_t^2; out[t,p] = y_t at observed rows.
//
// R1: __shfl_xor = LDS swizzle ~120cy/step -> DPP reduce.
// R2: readlane is int(int,int) — must bitcast.
// R3-R6: register prefetch pipelines collapsed by regalloc/scheduler.
// R7: global_load_lds ping-pong pipeline; 16-way LDS bank conflicts.
// R8: conflict-free lane*16 reads (conflicts 4.19M->0) but only -30us:
//     both buffers in ONE lds[] with runtime offset p*BUFB -> compiler
//     can't disprove DMA-write vs ds_read aliasing -> conservative
//     s_waitcnt vmcnt(0) BEFORE the in-loop ds_reads -> synchronous
//     issue->drain->read, ~1000+cy/block stall. 389us scan.
// R9: (a) two DISTINCT __shared__ arrays + 2x-unrolled loop (static buffer
//     choice) -> alias analysis sees disjoint objects -> only remaining
//     vmcnt(0) is inside __syncthreads, draining DMAs issued a full block
//     (~850cy) earlier. (b) Gram band via wave-uniform s_load into SGPRs
//     (P+blk*BANDPAD uniform, compile-time indices) — kills band DMA,
//     band ds_read, and 28 v_readlanes/block.

constexpr int N_IN    = 512;
constexpr int T       = 2048;
constexpr int N_OBS   = 256;
constexpr int D       = 8;            // linearization block size
constexpr int NBLK    = T / D;        // 256
constexpr int BANDPAD = 64;           // packed-band floats per block (28 used)

// Packed band layout for block b (t0=8b): entry k = x_{t0+i}.x_{t0+i+j},
// k = BOFF[i] + (j-1), i=0..6, j=1..7-i (28 entries).
__device__ constexpr int BOFF[8] = {0, 7, 13, 18, 22, 25, 27, 28};

// DPP add-reduce step; old=0 is the additive identity for invalid lanes.
#define DPP_ADD(v, ctrl, rmask)                                                \
    v += __int_as_float(__builtin_amdgcn_update_dpp(                           \
        0, __float_as_int(v), (ctrl), (rmask), 0xf, false))

__device__ __forceinline__ float wave64_sum_bcast(float v) {
    DPP_ADD(v, 0x111, 0xf); // row_shr:1
    DPP_ADD(v, 0x112, 0xf); // row_shr:2
    DPP_ADD(v, 0x114, 0xf); // row_shr:4
    DPP_ADD(v, 0x118, 0xf); // row_shr:8
    DPP_ADD(v, 0x142, 0xa); // row_bcast:15
    DPP_ADD(v, 0x143, 0xc); // row_bcast:31 -> lane63 = total
    return __int_as_float(__builtin_amdgcn_readlane(__float_as_int(v), 63));
}

__device__ __forceinline__ float dot8(const float4& u0, const float4& u1,
                                      const float4& v0, const float4& v1) {
    float p0 = fmaf(u0.x, v0.x, u0.y * v0.y);
    float p1 = fmaf(u0.z, v0.z, u0.w * v0.w);
    float p2 = fmaf(u1.x, v1.x, u1.y * v1.y);
    float p3 = fmaf(u1.z, v1.z, u1.w * v1.w);
    return (p0 + p1) + (p2 + p3);
}

// Async global->LDS DMA: per-lane global addr, wave-uniform LDS base,
// lane i lands at base + i*16 (m104/m108).
typedef __attribute__((address_space(3))) void       lds_t;
typedef const __attribute__((address_space(1))) void gbl_t;
__device__ __forceinline__ void dma16(const float* g, void* l) {
    __builtin_amdgcn_global_load_lds((gbl_t*)g, (lds_t*)l, 16, 0, 0);
}

// ---- Kernel 1: packed Gram band, one wave per 8-step block -----------------
__global__ __launch_bounds__(64) void gram_kernel(const float* __restrict__ X,
                                                  float* __restrict__ P) {
    const int b    = blockIdx.x;          // 0..NBLK-1
    const int lane = threadIdx.x;         // 0..63
    const int t0   = b * D;
    const float4* Xv = (const float4*)(X + (long)t0 * N_IN);
    float4 r[8][2];
    #pragma unroll
    for (int i = 0; i < 8; ++i) {
        r[i][0] = Xv[i * (N_IN / 4) + lane * 2 + 0];
        r[i][1] = Xv[i * (N_IN / 4) + lane * 2 + 1];
    }
    float s[28];
    #pragma unroll
    for (int i = 0; i < 7; ++i) {
        #pragma unroll
        for (int j = 1; j <= 7 - i; ++j) {
            s[BOFF[i] + j - 1] =
                wave64_sum_bcast(dot8(r[i][0], r[i][1], r[i + j][0], r[i + j][1]));
        }
    }
    if (lane == 0) {
        #pragma unroll
        for (int k = 0; k < 28; ++k) P[b * BANDPAD + k] = s[k];
    }
}

// ---- Kernel 2: the scan ----------------------------------------------------
// Two DISTINCT LDS objects: static buffer selection per unrolled half-iter
// lets alias analysis prove DMA writes (to one) don't touch ds_reads (of the
// other) -> no in-loop vmcnt(0); only the barrier's drain remains.
__global__ __launch_bounds__(256, 1) void oja_scan_kernel(
    const float* __restrict__ X,     // [T, N_IN]
    const float* __restrict__ Winit, // [N_OUT, N_IN]
    const float* __restrict__ theta, // [2]
    const int*   __restrict__ obs,   // [N_OBS]
    const float* __restrict__ P,     // [NBLK, BANDPAD] packed band (d_ws)
    float*       __restrict__ out)   // [T, N_OBS]
{
    __shared__ float4 bufA[D][128];  // 16 KB
    __shared__ float4 bufB[D][128];  // 16 KB

    const int tid  = threadIdx.x;
    const int wid  = tid >> 6;            // 0..3
    const int lane = tid & 63;
    const int wave = blockIdx.x * 4 + wid; // observed-row index; always < 256

    const int row = obs[wave];
    const float lr  = 1.0f / (float)N_IN;
    const float th0 = theta[0] * lr;
    const float th1 = theta[1] * lr;

    // Ownership (R8): lane owns elements [4l,4l+4) and [256+4l,256+4l+4).
    const float4* Wv = (const float4*)(Winit + (long)row * N_IN);
    float4 w0 = Wv[lane];
    float4 w1 = Wv[64 + lane];

    // Stage block blk's 8 x-rows into buf. Wave wid stages rows 2wid,2wid+1.
    auto stage = [&](float4 (&buf)[D][128], int blk) {
        const int t0b = blk * D;
        #pragma unroll
        for (int r = 2 * wid; r < 2 * wid + 2; ++r) {
            const float* g = X + (long)(t0b + r) * N_IN + lane * 4;
            dma16(g,       &buf[r][0]);    // elements [0,256): lane*16 B
            dma16(g + 256, &buf[r][64]);   // elements [256,512)
        }
    };

    // Process block blk out of buf (after the barrier that drained it).
    auto process = [&](float4 (&buf)[D][128], int blk) {
        // Gram band -> SGPRs: wave-uniform base, compile-time offsets.
        const float* pb = P + blk * BANDPAD;
        float bs[28];
        #pragma unroll
        for (int k = 0; k < 28; ++k) bs[k] = pb[k];

        // LDS -> registers, conflict-free (lane*16 within each half-row).
        float4 xr[D][2];
        #pragma unroll
        for (int r = 0; r < D; ++r) {
            xr[r][0] = buf[r][lane];
            xr[r][1] = buf[r][64 + lane];
        }

        // Boundary: Q_d = w_{t0} . x_{t0+d} (8 independent DPP chains).
        float q[D];
        #pragma unroll
        for (int d = 0; d < D; ++d)
            q[d] = wave64_sum_bcast(dot8(w0, w1, xr[d][0], xr[d][1]));

        // Eight steps: sigmoid + Q propagation (SGPR Gram scalars) + w update.
        const int t0 = blk * D;
        float z = q[0];
        #pragma unroll
        for (int i = 0; i < D; ++i) {
            const float y = __builtin_amdgcn_rcpf(1.0f + __expf(-z));
            if (lane == 0) out[(t0 + i) * N_OBS + wave] = y;

            const float a = th0 * y;
            const float b = fmaf(th1 * y, y, 1.0f);

            #pragma unroll
            for (int d = i + 1; d < D; ++d)
                q[d] = fmaf(b, q[d], a * bs[BOFF[i] + (d - i) - 1]);
            if (i < D - 1) z = q[i + 1];

            w0.x = fmaf(b, w0.x, a * xr[i][0].x);
            w0.y = fmaf(b, w0.y, a * xr[i][0].y);
            w0.z = fmaf(b, w0.z, a * xr[i][0].z);
            w0.w = fmaf(b, w0.w, a * xr[i][0].w);
            w1.x = fmaf(b, w1.x, a * xr[i][1].x);
            w1.y = fmaf(b, w1.y, a * xr[i][1].y);
            w1.z = fmaf(b, w1.z, a * xr[i][1].z);
            w1.w = fmaf(b, w1.w, a * xr[i][1].w);
        }
    };

    stage(bufA, 0);   // prologue

    for (int blk = 0; blk < NBLK; blk += 2) {
        __syncthreads();                 // drains bufA's DMAs (issued ~1 block ago)
        stage(bufB, blk + 1);            // into the OTHER named object
        process(bufA, blk);

        __syncthreads();                 // drains bufB's DMAs
        const int b2 = (blk + 2 < NBLK) ? (blk + 2) : (NBLK - 1);
        stage(bufA, b2);
        process(bufB, blk + 1);
    }
}

extern "C" void kernel_launch(void* const* d_in, const int* in_sizes, int n_in,
                              void* d_out, int out_size, void* d_ws, size_t ws_size,
                              hipStream_t stream) {
    const float* X     = (const float*)d_in[0];
    const float* Winit = (const float*)d_in[1];
    const float* theta = (const float*)d_in[2];
    const int*   obs   = (const int*)d_in[3];
    float*       out   = (float*)d_out;
    float*       P     = (float*)d_ws;   // NBLK*BANDPAD floats = 64 KB

    // Gram band: one wave per block.
    gram_kernel<<<NBLK, 64, 0, stream>>>(X, P);

    // Scan: 64 workgroups x 4 waves (one observed row per wave).
    oja_scan_kernel<<<64, 256, 0, stream>>>(X, Winit, theta, obs, P, out);
}

// Round 10
// 346.813 us; speedup vs baseline: 1.2978x; 1.2978x over previous
//
#include <hip/hip_runtime.h>

// CircuitModel: sequential Oja/Hebbian plasticity scan.
//   y_t = sigmoid(w_t.x_t); w_{t+1} = b_t*w_t + a_t*x_t,
//   a_t = lr*th0*y_t, b_t = 1 + lr*th1*y_t^2; out[t,p] = y_t at observed rows.
//
// R1: __shfl_xor = LDS swizzle ~120cy/step -> DPP reduce.
// R2: readlane is int(int,int) — must bitcast.
// R3-R6: compiler collapsed every register prefetch pipeline (loads sunk).
// R7-R9: LDS staging pipelines stuck at ~390us: barrier vmcnt(0) drains the
//     just-issued out-stores (~300cy/blk) + 4 waves re-read the whole 16KB
//     block from LDS (~950cy/blk shared pipe). R8 vs R9 neutrality proved
//     the stall was never compiler-alias vmcnt.
// R10: explicit vmcnt control, AITER-style. ALL loop VMEM is asm volatile:
//     23 global_load_dwordx4 (band+x) into a register double buffer, ONE
//     exec-masked batched y-store (lanes 0-7), then s_waitcnt vmcnt(1) with
//     the loaded values operand-tied ("+v") so uses can't float above it.
//     Loads get a full block (~800cy) of slack; stores are never waited on.
//     No LDS, no barriers; asm outputs pin the buffers in registers.

constexpr int N_IN    = 512;
constexpr int T       = 2048;
constexpr int N_OBS   = 256;
constexpr int D       = 8;            // linearization block size
constexpr int NBLK    = T / D;        // 256
constexpr int BANDPAD = 64;           // packed-band floats per block (28 used)

typedef float f4 __attribute__((ext_vector_type(4)));

// Packed band layout for block b (t0=8b): entry k = x_{t0+i}.x_{t0+i+j},
// k = BOFF[i] + (j-1), i=0..6, j=1..7-i (28 entries).
__device__ constexpr int BOFF[8] = {0, 7, 13, 18, 22, 25, 27, 28};

// DPP add-reduce step; old=0 is the additive identity for invalid lanes.
#define DPP_ADD(v, ctrl, rmask)                                                \
    v += __int_as_float(__builtin_amdgcn_update_dpp(                           \
        0, __float_as_int(v), (ctrl), (rmask), 0xf, false))

__device__ __forceinline__ float wave64_sum_bcast(float v) {
    DPP_ADD(v, 0x111, 0xf); // row_shr:1
    DPP_ADD(v, 0x112, 0xf); // row_shr:2
    DPP_ADD(v, 0x114, 0xf); // row_shr:4
    DPP_ADD(v, 0x118, 0xf); // row_shr:8
    DPP_ADD(v, 0x142, 0xa); // row_bcast:15
    DPP_ADD(v, 0x143, 0xc); // row_bcast:31 -> lane63 = total
    return __int_as_float(__builtin_amdgcn_readlane(__float_as_int(v), 63));
}

__device__ __forceinline__ float dot8(const f4& u0, const f4& u1,
                                      const f4& v0, const f4& v1) {
    float p0 = fmaf(u0.x, v0.x, u0.y * v0.y);
    float p1 = fmaf(u0.z, v0.z, u0.w * v0.w);
    float p2 = fmaf(u1.x, v1.x, u1.y * v1.y);
    float p3 = fmaf(u1.z, v1.z, u1.w * v1.w);
    return (p0 + p1) + (p2 + p3);
}

// ---- explicit-VMEM primitives ---------------------------------------------
#define GLOADX(dst, addr, offstr)                                              \
    asm volatile("global_load_dwordx4 %0, %1, off offset:" offstr              \
                 : "=v"(dst) : "v"(addr))

// Stage one block: 7 band dwordx4 (wave-uniform addr) + 16 x dwordx4.
// Exactly 23 vmem issues, in this program order (volatile order preserved).
__device__ __forceinline__ void stage23(f4 (&xb)[16], f4 (&bb)[7],
                                        const char* xa, const char* pb) {
    GLOADX(bb[0], pb, "0");   GLOADX(bb[1], pb, "16");
    GLOADX(bb[2], pb, "32");  GLOADX(bb[3], pb, "48");
    GLOADX(bb[4], pb, "64");  GLOADX(bb[5], pb, "80");
    GLOADX(bb[6], pb, "96");
    const char* a0 = xa;
    const char* a1 = xa + 4096;
    const char* a2 = xa + 8192;
    const char* a3 = xa + 12288;
    GLOADX(xb[0],  a0, "0");  GLOADX(xb[1],  a0, "1024");
    GLOADX(xb[2],  a0, "2048"); GLOADX(xb[3],  a0, "3072");
    GLOADX(xb[4],  a1, "0");  GLOADX(xb[5],  a1, "1024");
    GLOADX(xb[6],  a1, "2048"); GLOADX(xb[7],  a1, "3072");
    GLOADX(xb[8],  a2, "0");  GLOADX(xb[9],  a2, "1024");
    GLOADX(xb[10], a2, "2048"); GLOADX(xb[11], a2, "3072");
    GLOADX(xb[12], a3, "0");  GLOADX(xb[13], a3, "1024");
    GLOADX(xb[14], a3, "2048"); GLOADX(xb[15], a3, "3072");
}

// Operand-tied waitcnt: ties buffer values through the asm so no consumer
// can be scheduled above the wait. VM="1" leaves the newest store in flight.
#define TIE(VM, xb, bb)                                                        \
    asm volatile("s_waitcnt vmcnt(" VM ")"                                     \
        : "+v"(xb[0]), "+v"(xb[1]), "+v"(xb[2]),  "+v"(xb[3]),                 \
          "+v"(xb[4]), "+v"(xb[5]), "+v"(xb[6]),  "+v"(xb[7]),                 \
          "+v"(xb[8]), "+v"(xb[9]), "+v"(xb[10]), "+v"(xb[11]),                \
          "+v"(xb[12]),"+v"(xb[13]),"+v"(xb[14]), "+v"(xb[15]),                \
          "+v"(bb[0]), "+v"(bb[1]), "+v"(bb[2]),  "+v"(bb[3]),                 \
          "+v"(bb[4]), "+v"(bb[5]), "+v"(bb[6]))

// ---- Kernel 1: packed Gram band, one wave per 8-step block -----------------
__global__ __launch_bounds__(64) void gram_kernel(const float* __restrict__ X,
                                                  float* __restrict__ P) {
    const int b    = blockIdx.x;          // 0..NBLK-1
    const int lane = threadIdx.x;         // 0..63
    const int t0   = b * D;
    const f4* Xv = (const f4*)(X + (long)t0 * N_IN);
    f4 r[8][2];
    #pragma unroll
    for (int i = 0; i < 8; ++i) {
        r[i][0] = Xv[i * (N_IN / 4) + lane * 2 + 0];
        r[i][1] = Xv[i * (N_IN / 4) + lane * 2 + 1];
    }
    float s[28];
    #pragma unroll
    for (int i = 0; i < 7; ++i) {
        #pragma unroll
        for (int j = 1; j <= 7 - i; ++j) {
            s[BOFF[i] + j - 1] =
                wave64_sum_bcast(dot8(r[i][0], r[i][1], r[i + j][0], r[i + j][1]));
        }
    }
    if (lane == 0) {
        #pragma unroll
        for (int k = 0; k < 28; ++k) P[b * BANDPAD + k] = s[k];
    }
}

// ---- process one block from a register buffer ------------------------------
__device__ __forceinline__ void process_block(
    const f4 (&xb)[16], const f4 (&bb)[7], int t0, int lane, int wave,
    f4& w0, f4& w1, float th0, float th1, float* __restrict__ out)
{
    const float bs[28] = {
        bb[0].x, bb[0].y, bb[0].z, bb[0].w,
        bb[1].x, bb[1].y, bb[1].z, bb[1].w,
        bb[2].x, bb[2].y, bb[2].z, bb[2].w,
        bb[3].x, bb[3].y, bb[3].z, bb[3].w,
        bb[4].x, bb[4].y, bb[4].z, bb[4].w,
        bb[5].x, bb[5].y, bb[5].z, bb[5].w,
        bb[6].x, bb[6].y, bb[6].z, bb[6].w };

    // Boundary: Q_d = w_{t0} . x_{t0+d} (8 independent DPP chains).
    float q[D];
    #pragma unroll
    for (int d = 0; d < D; ++d)
        q[d] = wave64_sum_bcast(dot8(w0, w1, xb[2 * d], xb[2 * d + 1]));

    // Eight steps: sigmoid + Q propagation + rank-1 w update.
    // Lane i (i<8) collects y_i into ys for the batched store.
    float ys = 0.0f;
    float z = q[0];
    #pragma unroll
    for (int i = 0; i < D; ++i) {
        const float y = __builtin_amdgcn_rcpf(1.0f + __expf(-z));
        if (lane == i) ys = y;

        const float a = th0 * y;
        const float b = fmaf(th1 * y, y, 1.0f);

        #pragma unroll
        for (int d = i + 1; d < D; ++d)
            q[d] = fmaf(b, q[d], a * bs[BOFF[i] + (d - i) - 1]);
        if (i < D - 1) z = q[i + 1];

        w0.x = fmaf(b, w0.x, a * xb[2 * i].x);
        w0.y = fmaf(b, w0.y, a * xb[2 * i].y);
        w0.z = fmaf(b, w0.z, a * xb[2 * i].z);
        w0.w = fmaf(b, w0.w, a * xb[2 * i].w);
        w1.x = fmaf(b, w1.x, a * xb[2 * i + 1].x);
        w1.y = fmaf(b, w1.y, a * xb[2 * i + 1].y);
        w1.z = fmaf(b, w1.z, a * xb[2 * i + 1].z);
        w1.w = fmaf(b, w1.w, a * xb[2 * i + 1].w);
    }

    // One batched store: lanes 0..7 write y_0..y_7 (exec-masked in asm).
    float* oaddr = out + (size_t)(t0 + lane) * N_OBS + wave;
    asm volatile("s_mov_b64 vcc, exec\n\t"
                 "s_mov_b64 exec, 0xff\n\t"
                 "global_store_dword %0, %1, off\n\t"
                 "s_mov_b64 exec, vcc"
                 :: "v"(oaddr), "v"(ys) : "vcc");
}

// ---- Kernel 2: the scan ----------------------------------------------------
__global__ __launch_bounds__(256, 1) void oja_scan_kernel(
    const float* __restrict__ X,     // [T, N_IN]
    const float* __restrict__ Winit, // [N_OUT, N_IN]
    const float* __restrict__ theta, // [2]
    const int*   __restrict__ obs,   // [N_OBS]
    const float* __restrict__ P,     // [NBLK, BANDPAD] packed band (d_ws)
    float*       __restrict__ out)   // [T, N_OBS]
{
    const int tid  = threadIdx.x;
    const int wid  = tid >> 6;            // 0..3
    const int lane = tid & 63;
    const int wave = blockIdx.x * 4 + wid; // observed-row index; always < 256

    const int row = obs[wave];
    const float lr  = 1.0f / (float)N_IN;
    const float th0 = theta[0] * lr;
    const float th1 = theta[1] * lr;

    // Ownership (R8): lane owns elements [4l,4l+4) and [256+4l,256+4l+4).
    const f4* Wv = (const f4*)(Winit + (long)row * N_IN);
    f4 w0 = Wv[lane];
    f4 w1 = Wv[64 + lane];

    const char* xbase = (const char*)X + (size_t)lane * 16;
    const char* pbase = (const char*)P;

    // Register double buffers (pinned by asm outputs; ~250 VGPR total,
    // within the ~512 budget at launch_bounds(256,1)).
    f4 xA[16], xB[16], bA[7], bB[7];

    // Prologue: block 0 into A, full drain.
    stage23(xA, bA, xbase, pbase);
    TIE("0", xA, bA);

    for (int blk = 0; blk < NBLK; blk += 2) {
        // Half 1: stage blk+1 into B, process blk from A.
        // vmcnt: 23 loads + 1 store issued; wait vmcnt(1) drains the loads
        // (and any previous store), leaves the newest store in flight.
        const int b1 = (blk + 1 < NBLK) ? (blk + 1) : (NBLK - 1);
        stage23(xB, bB, xbase + (size_t)b1 * 16384, pbase + (size_t)b1 * 256);
        process_block(xA, bA, blk * D, lane, wave, w0, w1, th0, th1, out);
        TIE("1", xB, bB);

        // Half 2: stage blk+2 into A, process blk+1 from B.
        const int b2 = (blk + 2 < NBLK) ? (blk + 2) : (NBLK - 1);
        stage23(xA, bA, xbase + (size_t)b2 * 16384, pbase + (size_t)b2 * 256);
        process_block(xB, bB, (blk + 1) * D, lane, wave, w0, w1, th0, th1, out);
        TIE("1", xA, bA);
    }
}

extern "C" void kernel_launch(void* const* d_in, const int* in_sizes, int n_in,
                              void* d_out, int out_size, void* d_ws, size_t ws_size,
                              hipStream_t stream) {
    const float* X     = (const float*)d_in[0];
    const float* Winit = (const float*)d_in[1];
    const float* theta = (const float*)d_in[2];
    const int*   obs   = (const int*)d_in[3];
    float*       out   = (float*)d_out;
    float*       P     = (float*)d_ws;   // NBLK*BANDPAD floats = 64 KB

    // Gram band: one wave per block.
    gram_kernel<<<NBLK, 64, 0, stream>>>(X, P);

    // Scan: 64 workgroups x 4 waves (one observed row per wave).
    oja_scan_kernel<<<64, 256, 0, stream>>>(X, Winit, theta, obs, P, out);
}

// Round 11
// 291.936 us; speedup vs baseline: 1.5418x; 1.1880x over previous
//
#include <hip/hip_runtime.h>

// CircuitModel: sequential Oja/Hebbian plasticity scan.
//   y_t = sigmoid(w_t.x_t); w_{t+1} = b_t*w_t + a_t*x_t,
//   a_t = lr*th0*y_t, b_t = 1 + lr*th1*y_t^2; out[t,p] = y_t at observed rows.
//
// R1: __shfl_xor = LDS swizzle ~120cy/step -> DPP reduce.
// R2: readlane is int(int,int) — must bitcast.
// R3-R6: compiler collapsed every register prefetch pipeline.
// R7-R9: LDS pipelines stuck ~390us (store drain at barrier + 4x LDS re-read).
// R10: asm-volatile loads + operand-tied s_waitcnt vmcnt(1): 300us. But
//     VGPR_Count=72 proved the scheduler HOISTED process(xA)'s compute above
//     stage(xB) (compute is non-volatile; only asm is order-pinned) ->
//     TIE waited full load latency (~1300cy/blk).
// R11: PIN(xA): empty volatile asm tying xA after stage(xB). Volatile order
//     puts PIN after the loads; xA's consumers read PIN's outputs -> ALL
//     compute sits between load-issue and TIE. The volatile out-store
//     (dep chain = all y's) already pins compute before TIE. Band via
//     wave-uniform C++ loads (s_load/lgkmcnt, off the vmcnt books).

constexpr int N_IN    = 512;
constexpr int T       = 2048;
constexpr int N_OBS   = 256;
constexpr int D       = 8;            // linearization block size
constexpr int NBLK    = T / D;        // 256
constexpr int BANDPAD = 64;           // packed-band floats per block (28 used)

typedef float f4 __attribute__((ext_vector_type(4)));

// Packed band layout for block b (t0=8b): entry k = x_{t0+i}.x_{t0+i+j},
// k = BOFF[i] + (j-1), i=0..6, j=1..7-i (28 entries).
__device__ constexpr int BOFF[8] = {0, 7, 13, 18, 22, 25, 27, 28};

// DPP add-reduce step; old=0 is the additive identity for invalid lanes.
#define DPP_ADD(v, ctrl, rmask)                                                \
    v += __int_as_float(__builtin_amdgcn_update_dpp(                           \
        0, __float_as_int(v), (ctrl), (rmask), 0xf, false))

__device__ __forceinline__ float wave64_sum_bcast(float v) {
    DPP_ADD(v, 0x111, 0xf); // row_shr:1
    DPP_ADD(v, 0x112, 0xf); // row_shr:2
    DPP_ADD(v, 0x114, 0xf); // row_shr:4
    DPP_ADD(v, 0x118, 0xf); // row_shr:8
    DPP_ADD(v, 0x142, 0xa); // row_bcast:15
    DPP_ADD(v, 0x143, 0xc); // row_bcast:31 -> lane63 = total
    return __int_as_float(__builtin_amdgcn_readlane(__float_as_int(v), 63));
}

__device__ __forceinline__ float dot8(const f4& u0, const f4& u1,
                                      const f4& v0, const f4& v1) {
    float p0 = fmaf(u0.x, v0.x, u0.y * v0.y);
    float p1 = fmaf(u0.z, v0.z, u0.w * v0.w);
    float p2 = fmaf(u1.x, v1.x, u1.y * v1.y);
    float p3 = fmaf(u1.z, v1.z, u1.w * v1.w);
    return (p0 + p1) + (p2 + p3);
}

// ---- explicit-VMEM primitives ---------------------------------------------
#define GLOADX(dst, addr, offstr)                                              \
    asm volatile("global_load_dwordx4 %0, %1, off offset:" offstr              \
                 : "=v"(dst) : "v"(addr))

// Stage one block's 8 x-rows: exactly 16 vmem load issues, program-ordered.
__device__ __forceinline__ void stage16(f4 (&xb)[16], const char* xa) {
    const char* a0 = xa;
    const char* a1 = xa + 4096;
    const char* a2 = xa + 8192;
    const char* a3 = xa + 12288;
    GLOADX(xb[0],  a0, "0");    GLOADX(xb[1],  a0, "1024");
    GLOADX(xb[2],  a0, "2048"); GLOADX(xb[3],  a0, "3072");
    GLOADX(xb[4],  a1, "0");    GLOADX(xb[5],  a1, "1024");
    GLOADX(xb[6],  a1, "2048"); GLOADX(xb[7],  a1, "3072");
    GLOADX(xb[8],  a2, "0");    GLOADX(xb[9],  a2, "1024");
    GLOADX(xb[10], a2, "2048"); GLOADX(xb[11], a2, "3072");
    GLOADX(xb[12], a3, "0");    GLOADX(xb[13], a3, "1024");
    GLOADX(xb[14], a3, "2048"); GLOADX(xb[15], a3, "3072");
}

#define TIEBUF(ins, buf)                                                       \
    asm volatile(ins                                                           \
        : "+v"(buf[0]), "+v"(buf[1]), "+v"(buf[2]),  "+v"(buf[3]),             \
          "+v"(buf[4]), "+v"(buf[5]), "+v"(buf[6]),  "+v"(buf[7]),             \
          "+v"(buf[8]), "+v"(buf[9]), "+v"(buf[10]), "+v"(buf[11]),            \
          "+v"(buf[12]),"+v"(buf[13]),"+v"(buf[14]), "+v"(buf[15]))

// Pin: consumers of buf must schedule after this point (dataflow), and this
// point is after the preceding volatile loads (volatile order). Zero insts.
#define PIN(buf)      TIEBUF("", buf)
// Wait: drain all but the newest N outstanding vmem ops, tying buf's values.
#define WAIT1(buf)    TIEBUF("s_waitcnt vmcnt(1)", buf)
#define WAIT0(buf)    TIEBUF("s_waitcnt vmcnt(0)", buf)

// ---- Kernel 1: packed Gram band, one wave per 8-step block -----------------
__global__ __launch_bounds__(64) void gram_kernel(const float* __restrict__ X,
                                                  float* __restrict__ P) {
    const int b    = blockIdx.x;          // 0..NBLK-1
    const int lane = threadIdx.x;         // 0..63
    const int t0   = b * D;
    const f4* Xv = (const f4*)(X + (long)t0 * N_IN);
    f4 r[8][2];
    #pragma unroll
    for (int i = 0; i < 8; ++i) {
        r[i][0] = Xv[i * (N_IN / 4) + lane * 2 + 0];
        r[i][1] = Xv[i * (N_IN / 4) + lane * 2 + 1];
    }
    float s[28];
    #pragma unroll
    for (int i = 0; i < 7; ++i) {
        #pragma unroll
        for (int j = 1; j <= 7 - i; ++j) {
            s[BOFF[i] + j - 1] =
                wave64_sum_bcast(dot8(r[i][0], r[i][1], r[i + j][0], r[i + j][1]));
        }
    }
    if (lane == 0) {
        #pragma unroll
        for (int k = 0; k < 28; ++k) P[b * BANDPAD + k] = s[k];
    }
}

// ---- process one block from a register buffer ------------------------------
__device__ __forceinline__ void process_block(
    const f4 (&xb)[16], const float (&bs)[28], int t0, int lane, int wave,
    f4& w0, f4& w1, float th0, float th1, float* __restrict__ out)
{
    // Boundary: Q_d = w_{t0} . x_{t0+d} (8 independent DPP chains).
    float q[D];
    #pragma unroll
    for (int d = 0; d < D; ++d)
        q[d] = wave64_sum_bcast(dot8(w0, w1, xb[2 * d], xb[2 * d + 1]));

    // Eight steps: sigmoid + Q propagation + rank-1 w update.
    float ys = 0.0f;
    float z = q[0];
    #pragma unroll
    for (int i = 0; i < D; ++i) {
        const float y = __builtin_amdgcn_rcpf(1.0f + __expf(-z));
        if (lane == i) ys = y;

        const float a = th0 * y;
        const float b = fmaf(th1 * y, y, 1.0f);

        #pragma unroll
        for (int d = i + 1; d < D; ++d)
            q[d] = fmaf(b, q[d], a * bs[BOFF[i] + (d - i) - 1]);
        if (i < D - 1) z = q[i + 1];

        w0.x = fmaf(b, w0.x, a * xb[2 * i].x);
        w0.y = fmaf(b, w0.y, a * xb[2 * i].y);
        w0.z = fmaf(b, w0.z, a * xb[2 * i].z);
        w0.w = fmaf(b, w0.w, a * xb[2 * i].w);
        w1.x = fmaf(b, w1.x, a * xb[2 * i + 1].x);
        w1.y = fmaf(b, w1.y, a * xb[2 * i + 1].y);
        w1.z = fmaf(b, w1.z, a * xb[2 * i + 1].z);
        w1.w = fmaf(b, w1.w, a * xb[2 * i + 1].w);
    }

    // One batched store: lanes 0..7 write y_0..y_7 (exec-masked). Volatile:
    // stays before the following WAIT1, pinning the y dep-chain with it.
    float* oaddr = out + (size_t)(t0 + lane) * N_OBS + wave;
    asm volatile("s_mov_b64 vcc, exec\n\t"
                 "s_mov_b64 exec, 0xff\n\t"
                 "global_store_dword %0, %1, off\n\t"
                 "s_mov_b64 exec, vcc"
                 :: "v"(oaddr), "v"(ys) : "vcc");
}

__device__ __forceinline__ void load_band(float (&bs)[28], const float* pb) {
    #pragma unroll
    for (int k = 0; k < 28; ++k) bs[k] = pb[k];   // wave-uniform -> s_load
}

// ---- Kernel 2: the scan ----------------------------------------------------
__global__ __launch_bounds__(256, 1) void oja_scan_kernel(
    const float* __restrict__ X,     // [T, N_IN]
    const float* __restrict__ Winit, // [N_OUT, N_IN]
    const float* __restrict__ theta, // [2]
    const int*   __restrict__ obs,   // [N_OBS]
    const float* __restrict__ P,     // [NBLK, BANDPAD] packed band (d_ws)
    float*       __restrict__ out)   // [T, N_OBS]
{
    const int tid  = threadIdx.x;
    const int wid  = tid >> 6;            // 0..3
    const int lane = tid & 63;
    const int wave = blockIdx.x * 4 + wid; // observed-row index; always < 256

    const int row = obs[wave];
    const float lr  = 1.0f / (float)N_IN;
    const float th0 = theta[0] * lr;
    const float th1 = theta[1] * lr;

    // Ownership (R8): lane owns elements [4l,4l+4) and [256+4l,256+4l+4).
    const f4* Wv = (const f4*)(Winit + (long)row * N_IN);
    f4 w0 = Wv[lane];
    f4 w1 = Wv[64 + lane];

    const char* xbase = (const char*)X + (size_t)lane * 16;

    f4 xA[16], xB[16];
    float bsA[28], bsB[28];

    // Prologue: block 0 into A, full drain.
    stage16(xA, xbase);
    load_band(bsA, P);
    WAIT0(xA);

    for (int blk = 0; blk < NBLK; blk += 2) {
        // Half 1: stage blk+1 into B; PIN(A) forces process(A)'s compute
        // after the loads; WAIT1 drains B's 16 loads (issued ~1400cy ago),
        // leaving only the newest out-store in flight.
        const int b1 = (blk + 1 < NBLK) ? (blk + 1) : (NBLK - 1);
        stage16(xB, xbase + (size_t)b1 * 16384);
        load_band(bsB, P + (size_t)b1 * BANDPAD);
        PIN(xA);
        process_block(xA, bsA, blk * D, lane, wave, w0, w1, th0, th1, out);
        WAIT1(xB);

        // Half 2: symmetric.
        const int b2 = (blk + 2 < NBLK) ? (blk + 2) : (NBLK - 1);
        stage16(xA, xbase + (size_t)b2 * 16384);
        load_band(bsA, P + (size_t)b2 * BANDPAD);
        PIN(xB);
        process_block(xB, bsB, (blk + 1) * D, lane, wave, w0, w1, th0, th1, out);
        WAIT1(xA);
    }
}

extern "C" void kernel_launch(void* const* d_in, const int* in_sizes, int n_in,
                              void* d_out, int out_size, void* d_ws, size_t ws_size,
                              hipStream_t stream) {
    const float* X     = (const float*)d_in[0];
    const float* Winit = (const float*)d_in[1];
    const float* theta = (const float*)d_in[2];
    const int*   obs   = (const int*)d_in[3];
    float*       out   = (float*)d_out;
    float*       P     = (float*)d_ws;   // NBLK*BANDPAD floats = 64 KB

    // Gram band: one wave per block.
    gram_kernel<<<NBLK, 64, 0, stream>>>(X, P);

    // Scan: 64 workgroups x 4 waves (one observed row per wave).
    oja_scan_kernel<<<64, 256, 0, stream>>>(X, Winit, theta, obs, P, out);
}